// Round 4
// baseline (355.208 us; speedup 1.0000x reference)
//
#include <hip/hip_runtime.h>
#include <hip/hip_bf16.h>
#include <cmath>

typedef unsigned short u16;
typedef unsigned int   u32;

#define BB 4
#define CC 1024
#define TT 4096
#define HH 16
#define DD 64

using bf16x8 = __attribute__((ext_vector_type(8))) __bf16;
using f32x4  = __attribute__((ext_vector_type(4))) float;

union FragU { bf16x8 v; u16 u[8]; };

__device__ __forceinline__ float bf2f(u16 u) {
    union { u32 i; float f; } v; v.i = ((u32)u) << 16; return v.f;
}
__device__ __forceinline__ u16 f2bf(float f) {
    union { float f; u32 i; } v; v.f = f;
    u32 x = v.i;
    return (u16)((x + 0x7fffu + ((x >> 16) & 1u)) >> 16);  // RNE
}

// async global->LDS, 16B per lane: LDS dest = wave-uniform base + lane*16
__device__ __forceinline__ void gl_lds16(const u16* g, u16* l) {
    __builtin_amdgcn_global_load_lds(
        (const __attribute__((address_space(1))) void*)g,
        (__attribute__((address_space(3))) void*)l, 16, 0, 0);
}

// ---------------------------------------------------------------------------
// Fused prep: zone 0 (ids 0..1023)    x fp32 [B][C][T] -> xt bf16 [B][T][C]
//             zone 1 (ids 1024..5119) weight fp32->bf16 cvt (Wq,Wk,Wv,Wo)
//             zone 2 (ids 5120..5379) zero kvbuf+ksum (266240 floats)
// ---------------------------------------------------------------------------
__global__ __launch_bounds__(256) void prep_kernel(
    const float* __restrict__ x,
    const float* __restrict__ Wq, const float* __restrict__ Wk,
    const float* __restrict__ Wv, const float* __restrict__ Wo,
    u16* __restrict__ xt, u16* __restrict__ Wcat, u16* __restrict__ Wob,
    float* __restrict__ kvz)
{
    __shared__ u16 tile[64 * 258];
    const int id  = blockIdx.x;
    const int tid = threadIdx.x;

    if (id < 1024) {
        const int t0 = (id & 63) * 64;
        const int c0 = ((id >> 6) & 3) * 256;
        const int b  = id >> 8;
        const float* xb  = x  + (size_t)b * CC * TT;
        u16*         xtb = xt + (size_t)b * TT * CC;
        const int tcol = tid & 63;
        const int rw   = tid >> 6;
        #pragma unroll 8
        for (int p = 0; p < 64; ++p) {
            const int cr = p * 4 + rw;
            tile[tcol * 258 + cr] = f2bf(xb[(size_t)(c0 + cr) * TT + t0 + tcol]);
        }
        __syncthreads();
        const int cp = tid & 127;
        const int th = tid >> 7;
        #pragma unroll 8
        for (int q = 0; q < 32; ++q) {
            const int tr = q * 2 + th;
            const u32 v = *reinterpret_cast<const u32*>(&tile[tr * 258 + cp * 2]);
            *reinterpret_cast<u32*>(&xtb[(size_t)(t0 + tr) * CC + c0 + cp * 2]) = v;
        }
    } else if (id < 5120) {
        const int id2  = id - 1024;
        const int wsel = id2 >> 10;
        const int i    = ((id2 & 1023) * 256 + tid) * 4;
        const float* src = (wsel == 0) ? Wq : (wsel == 1) ? Wk : (wsel == 2) ? Wv : Wo;
        u16* dst = (wsel < 3) ? (Wcat + (size_t)wsel * CC * CC) : Wob;
        const float4 v = *reinterpret_cast<const float4*>(src + i);
        ushort4 o;
        o.x = f2bf(v.x); o.y = f2bf(v.y); o.z = f2bf(v.z); o.w = f2bf(v.w);
        *reinterpret_cast<ushort4*>(dst + i) = o;
    } else {
        const int idx = ((id - 5120) * 256 + tid) * 4;   // 260*1024 = 266240 exact
        *reinterpret_cast<float4*>(&kvz[idx]) = (float4){0.f, 0.f, 0.f, 0.f};
    }
}

// ---------------------------------------------------------------------------
// QKV GEMM, 256x256 tile, BK=64, 8 waves (2Mx4N), 512 threads, 128KiB LDS.
// 4-window counted-vmcnt schedule WITH read-ahead pipelining:
//   window = { [waits] ; STG ; MFMA(frags read in PREVIOUS window) ;
//              issue NEXT window's new fragment reads ; BAR }
//   quadrants (0,0)->(0,1)->(1,1)->(1,0); af double-set (af0 quad-row0,
//   af1 quad-row1), bf single set reloaded. Reads for a tile's w0 are
//   issued IN w0 (post-barrier, after vmcnt guarantees) -- the only
//   serialization bubble, once per K-tile.
//   Staging: w0: Bh0(j+1)->NXT; w1: Ah0(j+2)->CUR; w2: Bh1(j+2)->CUR;
//            w3: Ah1(j+2)->CUR.  vmcnt(4) at w3-start: outstanding=12,
//   oldest 8 = ALL of tile j+1; leaves {Ah0,Bh1}(j+2) in flight.
// Output identical: seg0 Q row-major elu+1; seg1/2 K/V transposed [b][c][t].
// ---------------------------------------------------------------------------
__device__ __forceinline__ bf16x8 ldfrag(const u16* Xs, int row, int kk, int quad, int l7) {
    return *reinterpret_cast<const bf16x8*>(&Xs[row * 64 + ((((kk << 2) | quad) ^ l7) << 3)]);
}

__global__ __launch_bounds__(512, 2) void qkv_kernel(
    const u16* __restrict__ A, const u16* __restrict__ W,
    const float* __restrict__ bq, const float* __restrict__ bk,
    const float* __restrict__ bv, u16* __restrict__ Ybf)
{
    __shared__ __align__(16) u16 As[2][256 * 64];   // 64 KiB
    __shared__ __align__(16) u16 Bs[2][256 * 64];   // 64 KiB

    const int tid  = threadIdx.x;
    const int w    = tid >> 6;          // 0..7
    const int lane = tid & 63;
    const int wm   = w >> 2;            // 0..1 : M wave row (128 rows each)
    const int wn   = w & 3;             // 0..3 : N wave col (64 cols each)
    const int quad = lane >> 4;
    const int l16  = lane & 15;
    const int l7   = l16 & 7;

    // XCD-aware swizzle: 768 blocks, 96 per XCD chunk (768 % 8 == 0)
    const int bid = blockIdx.x;
    const int wg  = (bid & 7) * 96 + (bid >> 3);
    const int m0  = (wg / 12) * 256;
    const int n0  = (wg % 12) * 256;

    const u16* Ag = A + (size_t)m0 * CC;
    const u16* Wg = W + (size_t)n0 * CC;

    // staging constants: wave w stages rows [h*128 + w*16, +16) of a half
    const int r8 = lane >> 3;                 // 0..7
    const int cg = ((lane & 7) ^ r8) * 8;     // pre-swizzled global k-group

#define STG(Xg, Xs, h, kt)                                                          \
    { _Pragma("unroll")                                                             \
      for (int s_ = 0; s_ < 2; ++s_)                                                \
        gl_lds16((Xg) + (size_t)((h) * 128 + w * 16 + s_ * 8 + r8) * CC             \
                     + (kt) * 64 + cg,                                              \
                 &(Xs)[((h) * 128 + w * 16 + s_ * 8) * 64]); }

#define BAR() { asm volatile("" ::: "memory"); __builtin_amdgcn_s_barrier(); \
                asm volatile("" ::: "memory"); }
#define LGKM0() asm volatile("s_waitcnt lgkmcnt(0)" ::: "memory")

    // prologue: tile0 all 4 halves (8 loads) + tile1 {Ah0,Bh1,Ah1} (6 loads)
    STG(Ag, As[0], 0, 0);    // Ah0 K0
    STG(Wg, Bs[0], 1, 0);    // Bh1 K0
    STG(Ag, As[0], 1, 0);    // Ah1 K0
    STG(Wg, Bs[0], 0, 0);    // Bh0 K0
    STG(Ag, As[1], 0, 1);    // Ah0 K1
    STG(Wg, Bs[1], 1, 1);    // Bh1 K1
    STG(Ag, As[1], 1, 1);    // Ah1 K1
    asm volatile("s_waitcnt vmcnt(6)" ::: "memory");  // tile0 landed
    BAR();

    f32x4 acc[8][4];
    #pragma unroll
    for (int i = 0; i < 8; ++i)
        #pragma unroll
        for (int jj = 0; jj < 4; ++jj) acc[i][jj] = (f32x4)0.0f;

    bf16x8 af0[4][2];  // A quadrant-row 0 frags (32 VGPR)
    bf16x8 af1[4][2];  // A quadrant-row 1 frags (32 VGPR)
    bf16x8 bf[2][2];   // single B col-pair set (16 VGPR), reloaded per window

#define LOAD_AF(AF, MH, CUR)                                                        \
    { _Pragma("unroll")                                                             \
      for (int i_ = 0; i_ < 4; ++i_)                                                \
        _Pragma("unroll")                                                           \
        for (int kk_ = 0; kk_ < 2; ++kk_)                                           \
          AF[i_][kk_] = ldfrag(&As[CUR][0],                                         \
              wm * 128 + (MH) * 64 + i_ * 16 + l16, kk_, quad, l7); }

#define LOAD_B(NH, CUR)                                                             \
    { _Pragma("unroll")                                                             \
      for (int jl_ = 0; jl_ < 2; ++jl_)                                             \
        _Pragma("unroll")                                                           \
        for (int kk_ = 0; kk_ < 2; ++kk_)                                           \
          bf[jl_][kk_] = ldfrag(&Bs[CUR][0],                                        \
              wn * 64 + (NH) * 32 + jl_ * 16 + l16, kk_, quad, l7); }

#define MFMA_Q(AF, MH, NH)                                                          \
    { __builtin_amdgcn_s_setprio(1);                                                \
      _Pragma("unroll")                                                             \
      for (int kk_ = 0; kk_ < 2; ++kk_)                                             \
        _Pragma("unroll")                                                           \
        for (int i_ = 0; i_ < 4; ++i_)                                              \
          _Pragma("unroll")                                                         \
          for (int jl_ = 0; jl_ < 2; ++jl_)                                         \
            acc[(MH) * 4 + i_][(NH) * 2 + jl_] =                                    \
              __builtin_amdgcn_mfma_f32_16x16x32_bf16(AF[i_][kk_],                  \
                  bf[jl_][kk_], acc[(MH) * 4 + i_][(NH) * 2 + jl_], 0, 0, 0);       \
      __builtin_amdgcn_s_setprio(0); }

    // VM3: 4 = steady, 0 = drain (tile 14), -1 = none (tile 15)
#define BLOCK(CUR, NXT, J, S0, S123, VM3)                                           \
  {                                                                                 \
    /* w0: self-read af0<-A0, bf<-B0 (tile-boundary bubble); MFMA(0,0);     */      \
    /*     read-ahead bf<-B1                                                */      \
    LOAD_AF(af0, 0, CUR); LOAD_B(0, CUR);                                           \
    if (S0)   { STG(Wg, Bs[NXT], 0, (J) + 1); }                                     \
    LGKM0();                                                                        \
    MFMA_Q(af0, 0, 0);                                                              \
    LOAD_B(1, CUR);                                                                 \
    BAR();                                                                          \
    /* w1: MFMA(0,1) on af0,bf(B1); read-ahead af1<-A1 */                           \
    LGKM0();                                                                        \
    if (S123) { STG(Ag, As[CUR], 0, (J) + 2); }                                     \
    MFMA_Q(af0, 0, 1);                                                              \
    LOAD_AF(af1, 1, CUR);                                                           \
    BAR();                                                                          \
    /* w2: MFMA(1,1) on af1,bf(B1); read-ahead bf<-B0 (reload) */                   \
    LGKM0();                                                                        \
    if (S123) { STG(Wg, Bs[CUR], 1, (J) + 2); }                                     \
    MFMA_Q(af1, 1, 1);                                                              \
    LOAD_B(0, CUR);                                                                 \
    BAR();                                                                          \
    /* w3: vmcnt guarantees tile J+1 landed; MFMA(1,0) on af1,bf(B0) */             \
    if ((VM3) == 4)      { asm volatile("s_waitcnt vmcnt(4)" ::: "memory"); }       \
    else if ((VM3) == 0) { asm volatile("s_waitcnt vmcnt(0)" ::: "memory"); }       \
    LGKM0();                                                                        \
    if (S123) { STG(Ag, As[CUR], 1, (J) + 2); }                                     \
    MFMA_Q(af1, 1, 0);                                                              \
    BAR();                                                                          \
  }

    // main loop: K = 1024 -> 16 K-tiles; steady tiles 0..13
    for (int j = 0; j < 14; j += 2) {
        BLOCK(0, 1, j,     1, 1, 4);
        BLOCK(1, 0, j + 1, 1, 1, 4);
    }
    BLOCK(0, 1, 14, 1, 0, 0);    // stage only Bh0(K15); drain at w3
    BLOCK(1, 0, 15, 0, 0, -1);   // pure compute

#undef BLOCK
#undef MFMA_Q
#undef LOAD_B
#undef LOAD_AF
#undef LGKM0
#undef BAR
#undef STG

    // ---------------- epilogue: identical semantics to before -----------------
    const int seg = n0 >> 10;          // 0..2 (tiles never straddle: 1024/256=4)
    const int nL  = n0 & 1023;
    if (seg == 0) {
        // Q: row-major [t][c], elu+1
        #pragma unroll
        for (int i = 0; i < 8; ++i) {
            const int row = m0 + wm * 128 + i * 16 + quad * 4;
            #pragma unroll
            for (int jj = 0; jj < 4; ++jj) {
                const int col = nL + wn * 64 + jj * 16 + l16;
                const float bvs = bq[col];
                #pragma unroll
                for (int r = 0; r < 4; ++r) {
                    float v = acc[i][jj][r] + bvs;
                    v = (v > 0.0f) ? (v + 1.0f) : __expf(v);
                    Ybf[(size_t)(row + r) * CC + col] = f2bf(v);
                }
            }
        }
    } else {
        // K/V: transposed [b][c][t] (t-contiguous), K gets elu+1
        const float* bp = (seg == 1) ? bk : bv;
        u16* Yt = Ybf + (size_t)seg * (size_t)(BB * TT) * CC;
        const int b  = m0 / TT;
        const int tb = m0 - b * TT + wm * 128;
        #pragma unroll
        for (int i = 0; i < 8; ++i) {
            const int t = tb + i * 16 + quad * 4;
            #pragma unroll
            for (int jj = 0; jj < 4; ++jj) {
                const int col = nL + wn * 64 + jj * 16 + l16;
                const float bvs = bp[col];
                ushort4 o;
                #pragma unroll
                for (int r = 0; r < 4; ++r) {
                    float v = acc[i][jj][r] + bvs;
                    if (seg == 1) v = (v > 0.0f) ? (v + 1.0f) : __expf(v);
                    ((u16*)&o)[r] = f2bf(v);
                }
                *reinterpret_cast<ushort4*>(
                    &Yt[((size_t)(b * CC + col)) * TT + t]) = o;
            }
        }
    }
}

// ---------------------------------------------------------------------------
// Out-proj GEMM (MODE 2, round-0 proven): 128x128 tile, +bias +fp32 residual,
// LDS-bounced fp32 stores along T.
// ---------------------------------------------------------------------------
template <int MODE>
__global__ __launch_bounds__(256, 2) void gemm_kernel(
    const u16* __restrict__ A, const u16* __restrict__ W,
    const float* __restrict__ b0, const float* __restrict__ b1,
    const float* __restrict__ b2, u16* __restrict__ Ybf,
    float* __restrict__ Yf, const float* __restrict__ xres,
    int M, int N, int K)
{
    __shared__ char smem[34048];           // As+Ws (32KB) / Cs (64*133*4)
    u16* As = (u16*)smem;                  // [128][64]
    u16* Ws = (u16*)(smem + 16384);        // [128][64]

    const int tid  = threadIdx.x;
    const int w    = tid >> 6;
    const int lane = tid & 63;
    const int wm = w >> 1, wn = w & 1;
    const int quad = lane >> 4, l16 = lane & 15;
    const int m0 = blockIdx.y * 128;
    const int n0 = blockIdx.x * 128;

    const int srow = lane >> 3;
    const int scol = ((lane & 7) ^ srow) * 8;

    f32x4 acc[4][4];
    #pragma unroll
    for (int i = 0; i < 4; ++i)
        #pragma unroll
        for (int j = 0; j < 4; ++j) acc[i][j] = (f32x4)0.0f;

    for (int k0 = 0; k0 < K; k0 += 64) {
        __syncthreads();
        #pragma unroll
        for (int s = 0; s < 4; ++s)
            gl_lds16(A + (size_t)(m0 + 32 * w + 8 * s + srow) * K + k0 + scol,
                     &As[(32 * w + 8 * s) * 64]);
        #pragma unroll
        for (int s = 0; s < 4; ++s)
            gl_lds16(W + (size_t)(n0 + 32 * w + 8 * s + srow) * K + k0 + scol,
                     &Ws[(32 * w + 8 * s) * 64]);
        __syncthreads();

        #pragma unroll
        for (int sub = 0; sub < 2; ++sub) {
            const int pg = (((sub << 2) | quad) ^ (l16 & 7)) * 8;
            bf16x8 af[4], bfr[4];
            #pragma unroll
            for (int i = 0; i < 4; ++i) {
                af[i]  = *reinterpret_cast<const bf16x8*>(&As[(wm * 64 + i * 16 + l16) * 64 + pg]);
                bfr[i] = *reinterpret_cast<const bf16x8*>(&Ws[(wn * 64 + i * 16 + l16) * 64 + pg]);
            }
            #pragma unroll
            for (int i = 0; i < 4; ++i)
                #pragma unroll
                for (int j = 0; j < 4; ++j)
                    acc[i][j] = __builtin_amdgcn_mfma_f32_16x16x32_bf16(af[i], bfr[j], acc[i][j], 0, 0, 0);
        }
    }

    if (MODE == 2) {
        float* Cs = (float*)smem;          // [64][133]
        const int b     = m0 / TT;
        const int tbase = m0 - b * TT;
        const int cl    = lane >> 4;
        #pragma unroll
        for (int hh = 0; hh < 2; ++hh) {
            __syncthreads();
            if (wm == hh) {
                #pragma unroll
                for (int i = 0; i < 4; ++i)
                    #pragma unroll
                    for (int j = 0; j < 4; ++j)
                        #pragma unroll
                        for (int r = 0; r < 4; ++r)
                            Cs[(i * 16 + quad * 4 + r) * 133 + wn * 64 + j * 16 + l16] = acc[i][j][r];
            }
            __syncthreads();
            #pragma unroll
            for (int p = 0; p < 8; ++p) {
                const int col = p * 16 + w * 4 + cl;
                const int tl  = l16 * 4;
                float4 v;
                v.x = Cs[(tl + 0) * 133 + col];
                v.y = Cs[(tl + 1) * 133 + col];
                v.z = Cs[(tl + 2) * 133 + col];
                v.w = Cs[(tl + 3) * 133 + col];
                const float bv = b0[n0 + col];
                const size_t base = ((size_t)b * CC + n0 + col) * TT + tbase + hh * 64 + tl;
                const float4 rx = *reinterpret_cast<const float4*>(&xres[base]);
                v.x += bv + rx.x; v.y += bv + rx.y;
                v.z += bv + rx.z; v.w += bv + rx.w;
                *reinterpret_cast<float4*>(&Yf[base]) = v;
            }
        }
    }
}

// ---------------------------------------------------------------------------
// kv[bh][d][e] = sum_t K[t][d]*V[t][e]; ksum[bh][d] = sum_t K[t][d].
// (round-0 proven form)
// ---------------------------------------------------------------------------
__global__ __launch_bounds__(256) void kv_kernel(
    const u16* __restrict__ Kt, const u16* __restrict__ Vt,
    float* __restrict__ kv, float* __restrict__ ksum)
{
    __shared__ u16 Ks[64 * 64];
    __shared__ u16 Vs[64 * 64];
    const int bh = blockIdx.x;
    const int b = bh >> 4, h = bh & 15;
    const int tc0 = blockIdx.y * 512;
    const int tid = threadIdx.x;
    const int w = tid >> 6, lane = tid & 63;
    const int quad = lane >> 4, l16 = lane & 15;

    const u16* Kg = Kt + ((size_t)(b * CC + h * DD)) * TT;
    const u16* Vg = Vt + ((size_t)(b * CC + h * DD)) * TT;

    const int srow = lane >> 3;
    const int scol = ((lane & 7) ^ srow) * 8;

    f32x4 acc[4];
    #pragma unroll
    for (int j = 0; j < 4; ++j) acc[j] = (f32x4)0.0f;
    f32x4 ks = (f32x4)0.0f;

    FragU ones;
    #pragma unroll
    for (int j = 0; j < 8; ++j) ones.u[j] = (l16 == 0) ? 0x3F80u : 0u;

    for (int it = 0; it < 8; ++it) {
        const int t0 = tc0 + it * 64;
        __syncthreads();
        #pragma unroll
        for (int s = 0; s < 2; ++s) {
            gl_lds16(Kg + (size_t)(16 * w + 8 * s + srow) * TT + t0 + scol,
                     &Ks[(16 * w + 8 * s) * 64]);
            gl_lds16(Vg + (size_t)(16 * w + 8 * s + srow) * TT + t0 + scol,
                     &Vs[(16 * w + 8 * s) * 64]);
        }
        __syncthreads();

        #pragma unroll
        for (int sub = 0; sub < 2; ++sub) {
            const int pg = (((sub << 2) | quad) ^ (l16 & 7)) * 8;
            const bf16x8 af = *reinterpret_cast<const bf16x8*>(
                &Ks[(w * 16 + l16) * 64 + pg]);       // A[d][t]
            #pragma unroll
            for (int e4 = 0; e4 < 4; ++e4) {
                const bf16x8 bfv = *reinterpret_cast<const bf16x8*>(
                    &Vs[(e4 * 16 + l16) * 64 + pg]);  // B[e][t]
                acc[e4] = __builtin_amdgcn_mfma_f32_16x16x32_bf16(af, bfv, acc[e4], 0, 0, 0);
            }
            ks = __builtin_amdgcn_mfma_f32_16x16x32_bf16(af, ones.v, ks, 0, 0, 0);
        }
    }

    float* kvb = kv + (size_t)bh * DD * DD;
    #pragma unroll
    for (int e4 = 0; e4 < 4; ++e4)
        #pragma unroll
        for (int r = 0; r < 4; ++r)
            atomicAdd(&kvb[(w * 16 + quad * 4 + r) * DD + e4 * 16 + l16], acc[e4][r]);
    if (l16 == 0) {
        #pragma unroll
        for (int r = 0; r < 4; ++r)
            atomicAdd(&ksum[bh * DD + w * 16 + quad * 4 + r], ks[r]);
    }
}

// ---------------------------------------------------------------------------
// attn: num = Q . kv, z via ksum-column MFMA, out = num/(z+1e-6) -> bf16.
// (round-0 proven form: direct scalar stores, L2 write-combines them)
// ---------------------------------------------------------------------------
__global__ __launch_bounds__(256) void attn_kernel(
    const u16* __restrict__ Q, const float* __restrict__ kv,
    const float* __restrict__ ksum, u16* __restrict__ attn)
{
    __shared__ u16 Qs[256 * 64];     // 32 KB
    __shared__ float kvs[DD * DD];   // 16 KB
    __shared__ float kss[DD];
    const int bh = blockIdx.x;
    const int b = bh >> 4, h = bh & 15;
    const int tb = blockIdx.y * 256;
    const int tid = threadIdx.x;
    const int w = tid >> 6, lane = tid & 63;
    const int quad = lane >> 4, l16 = lane & 15;

    {
        const int srow = lane >> 3;
        const int scol = ((lane & 7) ^ srow) * 8;
        const u16* Qg = Q + ((size_t)(b * TT + tb)) * CC + h * DD;
        #pragma unroll
        for (int p = 0; p < 8; ++p)
            gl_lds16(Qg + (size_t)(64 * w + 8 * p + srow) * CC + scol,
                     &Qs[(64 * w + 8 * p) * 64]);
    }
    {
        const float4* s4 = reinterpret_cast<const float4*>(kv + (size_t)bh * DD * DD);
        float4* d4 = reinterpret_cast<float4*>(kvs);
        #pragma unroll
        for (int p = 0; p < 4; ++p) d4[p * 256 + tid] = s4[p * 256 + tid];
        if (tid < DD) kss[tid] = ksum[bh * DD + tid];
    }
    __syncthreads();

    FragU bf[4][2], zb[2];
    #pragma unroll
    for (int ck = 0; ck < 2; ++ck) {
        #pragma unroll
        for (int nt = 0; nt < 4; ++nt)
            #pragma unroll
            for (int j = 0; j < 8; ++j)
                bf[nt][ck].u[j] = f2bf(kvs[(ck * 32 + quad * 8 + j) * DD + nt * 16 + l16]);
        #pragma unroll
        for (int j = 0; j < 8; ++j)
            zb[ck].u[j] = (l16 == 0) ? f2bf(kss[ck * 32 + quad * 8 + j]) : 0u;
    }

    f32x4 acc[4][4], zacc[4];
    #pragma unroll
    for (int i = 0; i < 4; ++i) {
        zacc[i] = (f32x4)0.0f;
        #pragma unroll
        for (int j = 0; j < 4; ++j) acc[i][j] = (f32x4)0.0f;
    }

    #pragma unroll
    for (int i = 0; i < 4; ++i) {
        const int trow = w * 64 + i * 16 + l16;
        #pragma unroll
        for (int ck = 0; ck < 2; ++ck) {
            const int pg = (((ck << 2) | quad) ^ (l16 & 7)) * 8;
            const bf16x8 af = *reinterpret_cast<const bf16x8*>(&Qs[trow * 64 + pg]);
            #pragma unroll
            for (int nt = 0; nt < 4; ++nt)
                acc[i][nt] = __builtin_amdgcn_mfma_f32_16x16x32_bf16(af, bf[nt][ck].v, acc[i][nt], 0, 0, 0);
            zacc[i] = __builtin_amdgcn_mfma_f32_16x16x32_bf16(af, zb[ck].v, zacc[i], 0, 0, 0);
        }
    }

    u16* obase = attn + ((size_t)b * TT) * CC + h * DD;
    #pragma unroll
    for (int i = 0; i < 4; ++i) {
        float inv[4];
        #pragma unroll
        for (int r = 0; r < 4; ++r) {
            const float zv = __shfl(zacc[i][r], lane & 48);
            inv[r] = 1.0f / (zv + 1e-6f);
        }
        #pragma unroll
        for (int nt = 0; nt < 4; ++nt) {
            #pragma unroll
            for (int r = 0; r < 4; ++r) {
                const int t = tb + w * 64 + i * 16 + quad * 4 + r;
                obase[(size_t)t * CC + nt * 16 + l16] = f2bf(acc[i][nt][r] * inv[r]);
            }
        }
    }
}

// ---------------------------------------------------------------------------
extern "C" void kernel_launch(void* const* d_in, const int* in_sizes, int n_in,
                              void* d_out, int out_size, void* d_ws, size_t ws_size,
                              hipStream_t stream)
{
    const float* x  = (const float*)d_in[0];
    const float* Wq = (const float*)d_in[1];
    const float* bq = (const float*)d_in[2];
    const float* Wk = (const float*)d_in[3];
    const float* bk = (const float*)d_in[4];
    const float* Wv = (const float*)d_in[5];
    const float* bv = (const float*)d_in[6];
    const float* Wo = (const float*)d_in[7];
    const float* bo = (const float*)d_in[8];
    float* out = (float*)d_out;

    const int M = BB * TT;                                   // 16384
    const size_t BUF  = (size_t)BB * TT * CC * sizeof(u16);  // 32 MiB
    const size_t WBUF = (size_t)CC * CC * sizeof(u16);       // 2 MiB

    char* ws = (char*)d_ws;
    u16* xt   = (u16*)(ws);                // reused as attn buffer
    u16* Qb   = (u16*)(ws + BUF);          // Q [t][c]; Kt,Vt [c][t] at +1,+2 BUF
    u16* Wcat = (u16*)(ws + 4 * BUF);      // [3072][1024] bf16
    u16* Wob  = (u16*)(ws + 4 * BUF + 3 * WBUF);
    float* kvbuf = (float*)(ws + 4 * BUF + 4 * WBUF);        // 1 MiB + 16 KiB (incl ksum)
    float* ksumb = kvbuf + (size_t)BB * HH * DD * DD;
    u16* attn = xt;

    // prep: transpose (1024) + weight cvt (4096) + kv zero (260)
    prep_kernel<<<5380, 256, 0, stream>>>(x, Wq, Wk, Wv, Wo, xt, Wcat, Wob, kvbuf);

    // fused QKV: 256x256 pipelined kernel, N = 3072 (Q row-major; K,V [c][t])
    qkv_kernel<<<768, 512, 0, stream>>>(xt, Wcat, bq, bk, bv, Qb);

    kv_kernel<<<dim3(BB * HH, TT / 512), 256, 0, stream>>>(
        Qb + (size_t)M * CC, Qb + 2 * (size_t)M * CC, kvbuf, ksumb);

    attn_kernel<<<dim3(BB * HH, TT / 256), 256, 0, stream>>>(Qb, kvbuf, ksumb, attn);

    gemm_kernel<2><<<dim3(CC / 128, M / 128), 256, 0, stream>>>(
        attn, Wob, bo, nullptr, nullptr, nullptr, out, x, M, CC, CC);
}

// Round 5
// 337.572 us; speedup vs baseline: 1.0522x; 1.0522x over previous
//
#include <hip/hip_runtime.h>
#include <hip/hip_bf16.h>
#include <cmath>

typedef unsigned short u16;
typedef unsigned int   u32;

#define BB 4
#define CC 1024
#define TT 4096
#define HH 16
#define DD 64

using bf16x8 = __attribute__((ext_vector_type(8))) __bf16;
using f32x4  = __attribute__((ext_vector_type(4))) float;

union FragU { bf16x8 v; u16 u[8]; };

__device__ __forceinline__ float bf2f(u16 u) {
    union { u32 i; float f; } v; v.i = ((u32)u) << 16; return v.f;
}
__device__ __forceinline__ u16 f2bf(float f) {
    union { float f; u32 i; } v; v.f = f;
    u32 x = v.i;
    return (u16)((x + 0x7fffu + ((x >> 16) & 1u)) >> 16);  // RNE
}

// async global->LDS, 16B per lane: LDS dest = wave-uniform base + lane*16
__device__ __forceinline__ void gl_lds16(const u16* g, u16* l) {
    __builtin_amdgcn_global_load_lds(
        (const __attribute__((address_space(1))) void*)g,
        (__attribute__((address_space(3))) void*)l, 16, 0, 0);
}

// ---------------------------------------------------------------------------
// Fused prep: zone 0 (ids 0..1023)    x fp32 [B][C][T] -> xt bf16 [B][T][C]
//             zone 1 (ids 1024..5119) weight fp32->bf16 cvt (Wq,Wk,Wv,Wo)
//             zone 2 (ids 5120..5379) zero kvbuf+ksum (266240 floats)
// ---------------------------------------------------------------------------
__global__ __launch_bounds__(256) void prep_kernel(
    const float* __restrict__ x,
    const float* __restrict__ Wq, const float* __restrict__ Wk,
    const float* __restrict__ Wv, const float* __restrict__ Wo,
    u16* __restrict__ xt, u16* __restrict__ Wcat, u16* __restrict__ Wob,
    float* __restrict__ kvz)
{
    __shared__ u16 tile[64 * 258];
    const int id  = blockIdx.x;
    const int tid = threadIdx.x;

    if (id < 1024) {
        const int t0 = (id & 63) * 64;
        const int c0 = ((id >> 6) & 3) * 256;
        const int b  = id >> 8;
        const float* xb  = x  + (size_t)b * CC * TT;
        u16*         xtb = xt + (size_t)b * TT * CC;
        const int tcol = tid & 63;
        const int rw   = tid >> 6;
        #pragma unroll 8
        for (int p = 0; p < 64; ++p) {
            const int cr = p * 4 + rw;
            tile[tcol * 258 + cr] = f2bf(xb[(size_t)(c0 + cr) * TT + t0 + tcol]);
        }
        __syncthreads();
        const int cp = tid & 127;
        const int th = tid >> 7;
        #pragma unroll 8
        for (int q = 0; q < 32; ++q) {
            const int tr = q * 2 + th;
            const u32 v = *reinterpret_cast<const u32*>(&tile[tr * 258 + cp * 2]);
            *reinterpret_cast<u32*>(&xtb[(size_t)(t0 + tr) * CC + c0 + cp * 2]) = v;
        }
    } else if (id < 5120) {
        const int id2  = id - 1024;
        const int wsel = id2 >> 10;
        const int i    = ((id2 & 1023) * 256 + tid) * 4;
        const float* src = (wsel == 0) ? Wq : (wsel == 1) ? Wk : (wsel == 2) ? Wv : Wo;
        u16* dst = (wsel < 3) ? (Wcat + (size_t)wsel * CC * CC) : Wob;
        const float4 v = *reinterpret_cast<const float4*>(src + i);
        ushort4 o;
        o.x = f2bf(v.x); o.y = f2bf(v.y); o.z = f2bf(v.z); o.w = f2bf(v.w);
        *reinterpret_cast<ushort4*>(dst + i) = o;
    } else {
        const int idx = ((id - 5120) * 256 + tid) * 4;   // 260*1024 = 266240 exact
        *reinterpret_cast<float4*>(&kvz[idx]) = (float4){0.f, 0.f, 0.f, 0.f};
    }
}

// ---------------------------------------------------------------------------
// kvfuse: per block (head-pair bx, 128-row m-tile my):
//   1) GEMM: K_tile = xt_tile @ Wk_n^T, V_tile = xt_tile @ Wv_n^T (A shared,
//      64 MFMA per k-step vs 12 staging loads -- denser than split GEMMs)
//   2) bias + elu+1 (K) / bias (V) -> transposed swizzled LDS tiles
//      Kl/Vl[c:128][t:128], u16 idx = c*128 + (t ^ ((c&15)*8))
//   3) kv contraction (kv_kernel math): kv[d][e] += sum_t K[d][t]V[e][t],
//      ksum[d] += sum_t K[d][t]; atomicAdd into global (pre-zeroed).
// Eliminates K/V materialization (64 MB store + 64 MB load) + kv_kernel.
// ---------------------------------------------------------------------------
__global__ __launch_bounds__(256, 2) void kvfuse_kernel(
    const u16* __restrict__ A, const u16* __restrict__ Wk,
    const u16* __restrict__ Wv, const float* __restrict__ bk,
    const float* __restrict__ bv, float* __restrict__ kv,
    float* __restrict__ ksum)
{
    __shared__ __align__(16) char smem[65536];
    u16* As  = (u16*)smem;              // [128][64] staging
    u16* WKs = (u16*)(smem + 16384);
    u16* WVs = (u16*)(smem + 32768);

    const int tid  = threadIdx.x;
    const int w    = tid >> 6;
    const int lane = tid & 63;
    const int wm = w >> 1, wn = w & 1;
    const int quad = lane >> 4, l16 = lane & 15;
    const int n0 = blockIdx.x * 128;     // head-pair channel base
    const int m0 = blockIdx.y * 128;     // b*T row base

    const int srow = lane >> 3;
    const int scol = ((lane & 7) ^ srow) * 8;

    f32x4 ak[4][4], av[4][4];
    #pragma unroll
    for (int i = 0; i < 4; ++i)
        #pragma unroll
        for (int j = 0; j < 4; ++j) { ak[i][j] = (f32x4)0.0f; av[i][j] = (f32x4)0.0f; }

    for (int k0 = 0; k0 < CC; k0 += 64) {
        __syncthreads();
        #pragma unroll
        for (int s = 0; s < 4; ++s) {
            gl_lds16(A  + (size_t)(m0 + 32 * w + 8 * s + srow) * CC + k0 + scol,
                     &As [(32 * w + 8 * s) * 64]);
            gl_lds16(Wk + (size_t)(n0 + 32 * w + 8 * s + srow) * CC + k0 + scol,
                     &WKs[(32 * w + 8 * s) * 64]);
            gl_lds16(Wv + (size_t)(n0 + 32 * w + 8 * s + srow) * CC + k0 + scol,
                     &WVs[(32 * w + 8 * s) * 64]);
        }
        __syncthreads();

        #pragma unroll
        for (int sub = 0; sub < 2; ++sub) {
            const int pg = (((sub << 2) | quad) ^ (l16 & 7)) * 8;
            bf16x8 af[4], bk4[4], bv4[4];
            #pragma unroll
            for (int i = 0; i < 4; ++i) {
                af[i]  = *reinterpret_cast<const bf16x8*>(&As [(wm * 64 + i * 16 + l16) * 64 + pg]);
                bk4[i] = *reinterpret_cast<const bf16x8*>(&WKs[(wn * 64 + i * 16 + l16) * 64 + pg]);
                bv4[i] = *reinterpret_cast<const bf16x8*>(&WVs[(wn * 64 + i * 16 + l16) * 64 + pg]);
            }
            #pragma unroll
            for (int i = 0; i < 4; ++i)
                #pragma unroll
                for (int j = 0; j < 4; ++j) {
                    ak[i][j] = __builtin_amdgcn_mfma_f32_16x16x32_bf16(af[i], bk4[j], ak[i][j], 0, 0, 0);
                    av[i][j] = __builtin_amdgcn_mfma_f32_16x16x32_bf16(af[i], bv4[j], av[i][j], 0, 0, 0);
                }
        }
    }

    // ---- phase 2: activation + transposed swizzled LDS store ----
    __syncthreads();                       // all waves done reading staging
    u16* Kl = (u16*)smem;                  // [c:128][t:128] swizzled
    u16* Vl = (u16*)(smem + 32768);

    float bkk[4], bvv[4];
    #pragma unroll
    for (int j = 0; j < 4; ++j) {
        bkk[j] = bk[n0 + wn * 64 + j * 16 + l16];
        bvv[j] = bv[n0 + wn * 64 + j * 16 + l16];
    }
    #pragma unroll
    for (int i = 0; i < 4; ++i) {
        const int t4 = wm * 64 + i * 16 + quad * 4;
        #pragma unroll
        for (int j = 0; j < 4; ++j) {
            const int c    = wn * 64 + j * 16 + l16;
            const int toff = t4 ^ ((c & 15) * 8);
            ushort4 oK, oV;
            #pragma unroll
            for (int r = 0; r < 4; ++r) {
                float vK = ak[i][j][r] + bkk[j];
                vK = (vK > 0.0f) ? (vK + 1.0f) : __expf(vK);
                ((u16*)&oK)[r] = f2bf(vK);
                ((u16*)&oV)[r] = f2bf(av[i][j][r] + bvv[j]);
            }
            *reinterpret_cast<ushort4*>(&Kl[c * 128 + toff]) = oK;
            *reinterpret_cast<ushort4*>(&Vl[c * 128 + toff]) = oV;
        }
    }
    __syncthreads();

    // ---- phase 3: kv contraction (kv_kernel fragment math) ----
    const int hh    = w >> 1;              // head within pair
    const int dbase = (w & 1) * 32;        // this wave: d-tiles dbase, dbase+16
    const int b     = m0 >> 12;            // m0 / TT
    const int bh    = b * HH + blockIdx.x * 2 + hh;

    FragU ones;
    #pragma unroll
    for (int j = 0; j < 8; ++j) ones.u[j] = (l16 == 0) ? 0x3F80u : 0u;

    f32x4 ckv[2][4], cks[2];
    #pragma unroll
    for (int s = 0; s < 2; ++s) {
        cks[s] = (f32x4)0.0f;
        #pragma unroll
        for (int e4 = 0; e4 < 4; ++e4) ckv[s][e4] = (f32x4)0.0f;
    }

    #pragma unroll
    for (int kt = 0; kt < 4; ++kt) {
        const int tg = kt * 32 + quad * 8;
        #pragma unroll
        for (int s = 0; s < 2; ++s) {
            const int ca = hh * 64 + dbase + s * 16 + l16;      // (ca&15)==l16
            const bf16x8 af = *reinterpret_cast<const bf16x8*>(
                &Kl[ca * 128 + (tg ^ (l16 * 8))]);
            #pragma unroll
            for (int e4 = 0; e4 < 4; ++e4) {
                const int cb = hh * 64 + e4 * 16 + l16;
                const bf16x8 bfv = *reinterpret_cast<const bf16x8*>(
                    &Vl[cb * 128 + (tg ^ (l16 * 8))]);
                ckv[s][e4] = __builtin_amdgcn_mfma_f32_16x16x32_bf16(af, bfv, ckv[s][e4], 0, 0, 0);
            }
            cks[s] = __builtin_amdgcn_mfma_f32_16x16x32_bf16(af, ones.v, cks[s], 0, 0, 0);
        }
    }

    float* kvb = kv + (size_t)bh * DD * DD;
    #pragma unroll
    for (int s = 0; s < 2; ++s)
        #pragma unroll
        for (int e4 = 0; e4 < 4; ++e4)
            #pragma unroll
            for (int r = 0; r < 4; ++r)
                atomicAdd(&kvb[(dbase + s * 16 + quad * 4 + r) * DD + e4 * 16 + l16],
                          ckv[s][e4][r]);
    if (l16 == 0) {
        #pragma unroll
        for (int s = 0; s < 2; ++s)
            #pragma unroll
            for (int r = 0; r < 4; ++r)
                atomicAdd(&ksum[bh * DD + dbase + s * 16 + quad * 4 + r], cks[s][r]);
    }
}

// ---------------------------------------------------------------------------
// qattn: Q-GEMM (round-0 structure, N=1024) with attn fused in the epilogue:
//   Q tile (bias+elu+1) -> swizzled LDS Qt[t:128][c:128]
//   (idx = t*128 + (c ^ ((t&7)*8)))
//   then per wave (head hh=w>>1, t-half th=w&1): num = Q.kv, z = Q.ksum,
//   out = num/(z+1e-6) -> bf16 attn tile (attn_kernel math, kv from global).
// Eliminates Q materialization (32 MB store + 32 MB load) + attn launch.
// ---------------------------------------------------------------------------
__global__ __launch_bounds__(256, 2) void qattn_kernel(
    const u16* __restrict__ A, const u16* __restrict__ Wq,
    const float* __restrict__ bq, const float* __restrict__ kv,
    const float* __restrict__ ksum, u16* __restrict__ attnO)
{
    __shared__ __align__(16) char smem[32768];
    u16* As = (u16*)smem;                  // [128][64]
    u16* Ws = (u16*)(smem + 16384);

    const int tid  = threadIdx.x;
    const int w    = tid >> 6;
    const int lane = tid & 63;
    const int wm = w >> 1, wn = w & 1;
    const int quad = lane >> 4, l16 = lane & 15;
    const int l7 = l16 & 7;
    const int n0 = blockIdx.x * 128;
    const int m0 = blockIdx.y * 128;

    const int srow = lane >> 3;
    const int scol = ((lane & 7) ^ srow) * 8;

    f32x4 acc[4][4];
    #pragma unroll
    for (int i = 0; i < 4; ++i)
        #pragma unroll
        for (int j = 0; j < 4; ++j) acc[i][j] = (f32x4)0.0f;

    for (int k0 = 0; k0 < CC; k0 += 64) {
        __syncthreads();
        #pragma unroll
        for (int s = 0; s < 4; ++s) {
            gl_lds16(A  + (size_t)(m0 + 32 * w + 8 * s + srow) * CC + k0 + scol,
                     &As[(32 * w + 8 * s) * 64]);
            gl_lds16(Wq + (size_t)(n0 + 32 * w + 8 * s + srow) * CC + k0 + scol,
                     &Ws[(32 * w + 8 * s) * 64]);
        }
        __syncthreads();

        #pragma unroll
        for (int sub = 0; sub < 2; ++sub) {
            const int pg = (((sub << 2) | quad) ^ l7) * 8;
            bf16x8 af[4], bfr[4];
            #pragma unroll
            for (int i = 0; i < 4; ++i) {
                af[i]  = *reinterpret_cast<const bf16x8*>(&As[(wm * 64 + i * 16 + l16) * 64 + pg]);
                bfr[i] = *reinterpret_cast<const bf16x8*>(&Ws[(wn * 64 + i * 16 + l16) * 64 + pg]);
            }
            #pragma unroll
            for (int i = 0; i < 4; ++i)
                #pragma unroll
                for (int j = 0; j < 4; ++j)
                    acc[i][j] = __builtin_amdgcn_mfma_f32_16x16x32_bf16(af[i], bfr[j], acc[i][j], 0, 0, 0);
        }
    }

    // ---- Q activation -> swizzled LDS tile ----
    __syncthreads();
    u16* Qt = (u16*)smem;                  // [t:128][c:128] swizzled
    float bqq[4];
    #pragma unroll
    for (int j = 0; j < 4; ++j) bqq[j] = bq[n0 + wn * 64 + j * 16 + l16];
    #pragma unroll
    for (int i = 0; i < 4; ++i) {
        #pragma unroll
        for (int j = 0; j < 4; ++j) {
            const int c = wn * 64 + j * 16 + l16;
            #pragma unroll
            for (int r = 0; r < 4; ++r) {
                const int t = wm * 64 + i * 16 + quad * 4 + r;
                float v = acc[i][j][r] + bqq[j];
                v = (v > 0.0f) ? (v + 1.0f) : __expf(v);
                Qt[t * 128 + (c ^ ((t & 7) * 8))] = f2bf(v);
            }
        }
    }
    __syncthreads();

    // ---- attn epilogue: wave -> head hh, t-half th ----
    const int hh = w >> 1, th = w & 1;
    const int b  = m0 >> 12;
    const int bh = b * HH + blockIdx.x * 2 + hh;
    const float* kvh = kv + (size_t)bh * DD * DD;

    FragU bf[4][2], zb[2];
    #pragma unroll
    for (int ck = 0; ck < 2; ++ck) {
        #pragma unroll
        for (int nt = 0; nt < 4; ++nt)
            #pragma unroll
            for (int j = 0; j < 8; ++j)
                bf[nt][ck].u[j] = f2bf(kvh[(ck * 32 + quad * 8 + j) * DD + nt * 16 + l16]);
        #pragma unroll
        for (int j = 0; j < 8; ++j)
            zb[ck].u[j] = (l16 == 0) ? f2bf(ksum[bh * DD + ck * 32 + quad * 8 + j]) : 0u;
    }

    f32x4 a2[4][4], za[4];
    #pragma unroll
    for (int i = 0; i < 4; ++i) {
        za[i] = (f32x4)0.0f;
        #pragma unroll
        for (int j = 0; j < 4; ++j) a2[i][j] = (f32x4)0.0f;
    }

    #pragma unroll
    for (int i = 0; i < 4; ++i) {
        const int trow = th * 64 + i * 16 + l16;
        #pragma unroll
        for (int ck = 0; ck < 2; ++ck) {
            const bf16x8 af = *reinterpret_cast<const bf16x8*>(
                &Qt[trow * 128 + (((hh * 8 + ck * 4 + quad) ^ l7) * 8)]);
            #pragma unroll
            for (int nt = 0; nt < 4; ++nt)
                a2[i][nt] = __builtin_amdgcn_mfma_f32_16x16x32_bf16(af, bf[nt][ck].v, a2[i][nt], 0, 0, 0);
            za[i] = __builtin_amdgcn_mfma_f32_16x16x32_bf16(af, zb[ck].v, za[i], 0, 0, 0);
        }
    }

    #pragma unroll
    for (int i = 0; i < 4; ++i) {
        float inv[4];
        #pragma unroll
        for (int r = 0; r < 4; ++r) {
            const float zv = __shfl(za[i][r], lane & 48);
            inv[r] = 1.0f / (zv + 1e-6f);
        }
        #pragma unroll
        for (int nt = 0; nt < 4; ++nt) {
            #pragma unroll
            for (int r = 0; r < 4; ++r) {
                const size_t row = (size_t)(m0 + th * 64 + i * 16 + quad * 4 + r);
                const int    col = n0 + hh * 64 + nt * 16 + l16;
                attnO[row * CC + col] = f2bf(a2[i][nt][r] * inv[r]);
            }
        }
    }
}

// ---------------------------------------------------------------------------
// Out-proj GEMM (MODE 2, round-0 proven): 128x128 tile, +bias +fp32 residual,
// LDS-bounced fp32 stores along T.
// ---------------------------------------------------------------------------
template <int MODE>
__global__ __launch_bounds__(256, 2) void gemm_kernel(
    const u16* __restrict__ A, const u16* __restrict__ W,
    const float* __restrict__ b0, const float* __restrict__ b1,
    const float* __restrict__ b2, u16* __restrict__ Ybf,
    float* __restrict__ Yf, const float* __restrict__ xres,
    int M, int N, int K)
{
    __shared__ char smem[34048];           // As+Ws (32KB) / Cs (64*133*4)
    u16* As = (u16*)smem;                  // [128][64]
    u16* Ws = (u16*)(smem + 16384);        // [128][64]

    const int tid  = threadIdx.x;
    const int w    = tid >> 6;
    const int lane = tid & 63;
    const int wm = w >> 1, wn = w & 1;
    const int quad = lane >> 4, l16 = lane & 15;
    const int m0 = blockIdx.y * 128;
    const int n0 = blockIdx.x * 128;

    const int srow = lane >> 3;
    const int scol = ((lane & 7) ^ srow) * 8;

    f32x4 acc[4][4];
    #pragma unroll
    for (int i = 0; i < 4; ++i)
        #pragma unroll
        for (int j = 0; j < 4; ++j) acc[i][j] = (f32x4)0.0f;

    for (int k0 = 0; k0 < K; k0 += 64) {
        __syncthreads();
        #pragma unroll
        for (int s = 0; s < 4; ++s)
            gl_lds16(A + (size_t)(m0 + 32 * w + 8 * s + srow) * K + k0 + scol,
                     &As[(32 * w + 8 * s) * 64]);
        #pragma unroll
        for (int s = 0; s < 4; ++s)
            gl_lds16(W + (size_t)(n0 + 32 * w + 8 * s + srow) * K + k0 + scol,
                     &Ws[(32 * w + 8 * s) * 64]);
        __syncthreads();

        #pragma unroll
        for (int sub = 0; sub < 2; ++sub) {
            const int pg = (((sub << 2) | quad) ^ (l16 & 7)) * 8;
            bf16x8 af[4], bfr[4];
            #pragma unroll
            for (int i = 0; i < 4; ++i) {
                af[i]  = *reinterpret_cast<const bf16x8*>(&As[(wm * 64 + i * 16 + l16) * 64 + pg]);
                bfr[i] = *reinterpret_cast<const bf16x8*>(&Ws[(wn * 64 + i * 16 + l16) * 64 + pg]);
            }
            #pragma unroll
            for (int i = 0; i < 4; ++i)
                #pragma unroll
                for (int j = 0; j < 4; ++j)
                    acc[i][j] = __builtin_amdgcn_mfma_f32_16x16x32_bf16(af[i], bfr[j], acc[i][j], 0, 0, 0);
        }
    }

    if (MODE == 2) {
        float* Cs = (float*)smem;          // [64][133]
        const int b     = m0 / TT;
        const int tbase = m0 - b * TT;
        const int cl    = lane >> 4;
        #pragma unroll
        for (int hh = 0; hh < 2; ++hh) {
            __syncthreads();
            if (wm == hh) {
                #pragma unroll
                for (int i = 0; i < 4; ++i)
                    #pragma unroll
                    for (int j = 0; j < 4; ++j)
                        #pragma unroll
                        for (int r = 0; r < 4; ++r)
                            Cs[(i * 16 + quad * 4 + r) * 133 + wn * 64 + j * 16 + l16] = acc[i][j][r];
            }
            __syncthreads();
            #pragma unroll
            for (int p = 0; p < 8; ++p) {
                const int col = p * 16 + w * 4 + cl;
                const int tl  = l16 * 4;
                float4 v;
                v.x = Cs[(tl + 0) * 133 + col];
                v.y = Cs[(tl + 1) * 133 + col];
                v.z = Cs[(tl + 2) * 133 + col];
                v.w = Cs[(tl + 3) * 133 + col];
                const float bv = b0[n0 + col];
                const size_t base = ((size_t)b * CC + n0 + col) * TT + tbase + hh * 64 + tl;
                const float4 rx = *reinterpret_cast<const float4*>(&xres[base]);
                v.x += bv + rx.x; v.y += bv + rx.y;
                v.z += bv + rx.z; v.w += bv + rx.w;
                *reinterpret_cast<float4*>(&Yf[base]) = v;
            }
        }
    }
}

// ---------------------------------------------------------------------------
extern "C" void kernel_launch(void* const* d_in, const int* in_sizes, int n_in,
                              void* d_out, int out_size, void* d_ws, size_t ws_size,
                              hipStream_t stream)
{
    const float* x  = (const float*)d_in[0];
    const float* Wq = (const float*)d_in[1];
    const float* bq = (const float*)d_in[2];
    const float* Wk = (const float*)d_in[3];
    const float* bk = (const float*)d_in[4];
    const float* Wv = (const float*)d_in[5];
    const float* bv = (const float*)d_in[6];
    const float* Wo = (const float*)d_in[7];
    const float* bo = (const float*)d_in[8];
    float* out = (float*)d_out;

    const int M = BB * TT;                                   // 16384
    const size_t BUF  = (size_t)BB * TT * CC * sizeof(u16);  // 32 MiB
    const size_t WBUF = (size_t)CC * CC * sizeof(u16);       // 2 MiB

    char* ws = (char*)d_ws;
    u16* xt   = (u16*)(ws);                // xt bf16 [B*T][C]
    u16* Qb   = (u16*)(ws + BUF);          // attn output [B*T][C]
    u16* Wcat = (u16*)(ws + 4 * BUF);      // [3072][1024] bf16 (Q,K,V)
    u16* Wob  = (u16*)(ws + 4 * BUF + 3 * WBUF);
    float* kvbuf = (float*)(ws + 4 * BUF + 4 * WBUF);        // 1 MiB + 16 KiB (incl ksum)
    float* ksumb = kvbuf + (size_t)BB * HH * DD * DD;

    // prep: transpose (1024) + weight cvt (4096) + kv zero (260)
    prep_kernel<<<5380, 256, 0, stream>>>(x, Wq, Wk, Wv, Wo, xt, Wcat, Wob, kvbuf);

    // fused K/V GEMM + kv/ksum contraction (atomic accumulate)
    kvfuse_kernel<<<dim3(CC / 128, M / 128), 256, 0, stream>>>(
        xt, Wcat + (size_t)CC * CC, Wcat + 2 * (size_t)CC * CC, bk, bv, kvbuf, ksumb);

    // fused Q GEMM + attention epilogue -> attn tile in Qb
    qattn_kernel<<<dim3(CC / 128, M / 128), 256, 0, stream>>>(
        xt, Wcat, bq, kvbuf, ksumb, Qb);

    // out-proj + bias + residual -> fp32 [B][C][T]
    gemm_kernel<2><<<dim3(CC / 128, M / 128), 256, 0, stream>>>(
        Qb, Wob, bo, nullptr, nullptr, nullptr, out, x, M, CC, CC);
}

// Round 6
// 322.277 us; speedup vs baseline: 1.1022x; 1.0475x over previous
//
#include <hip/hip_runtime.h>
#include <hip/hip_bf16.h>
#include <cmath>

typedef unsigned short u16;
typedef unsigned int   u32;

#define BB 4
#define CC 1024
#define TT 4096
#define HH 16
#define DD 64

using bf16x8 = __attribute__((ext_vector_type(8))) __bf16;
using f32x4  = __attribute__((ext_vector_type(4))) float;

union FragU { bf16x8 v; u16 u[8]; };

__device__ __forceinline__ float bf2f(u16 u) {
    union { u32 i; float f; } v; v.i = ((u32)u) << 16; return v.f;
}
__device__ __forceinline__ u16 f2bf(float f) {
    union { float f; u32 i; } v; v.f = f;
    u32 x = v.i;
    return (u16)((x + 0x7fffu + ((x >> 16) & 1u)) >> 16);  // RNE
}

// async global->LDS, 16B per lane: LDS dest = wave-uniform base + lane*16
__device__ __forceinline__ void gl_lds16(const u16* g, u16* l) {
    __builtin_amdgcn_global_load_lds(
        (const __attribute__((address_space(1))) void*)g,
        (__attribute__((address_space(3))) void*)l, 16, 0, 0);
}

// ---------------------------------------------------------------------------
// Fused prep: zone 0 (ids 0..1023)    x fp32 [B][C][T] -> xt bf16 [B][T][C]
//             zone 1 (ids 1024..5119) weight fp32->bf16 cvt (Wq,Wk,Wv,Wo)
//             zone 2 (ids 5120..5379) zero kvbuf+ksum (266240 floats)
// ---------------------------------------------------------------------------
__global__ __launch_bounds__(256) void prep_kernel(
    const float* __restrict__ x,
    const float* __restrict__ Wq, const float* __restrict__ Wk,
    const float* __restrict__ Wv, const float* __restrict__ Wo,
    u16* __restrict__ xt, u16* __restrict__ Wcat, u16* __restrict__ Wob,
    float* __restrict__ kvz)
{
    __shared__ u16 tile[64 * 258];
    const int id  = blockIdx.x;
    const int tid = threadIdx.x;

    if (id < 1024) {
        const int t0 = (id & 63) * 64;
        const int c0 = ((id >> 6) & 3) * 256;
        const int b  = id >> 8;
        const float* xb  = x  + (size_t)b * CC * TT;
        u16*         xtb = xt + (size_t)b * TT * CC;
        const int tcol = tid & 63;
        const int rw   = tid >> 6;
        #pragma unroll 8
        for (int p = 0; p < 64; ++p) {
            const int cr = p * 4 + rw;
            tile[tcol * 258 + cr] = f2bf(xb[(size_t)(c0 + cr) * TT + t0 + tcol]);
        }
        __syncthreads();
        const int cp = tid & 127;
        const int th = tid >> 7;
        #pragma unroll 8
        for (int q = 0; q < 32; ++q) {
            const int tr = q * 2 + th;
            const u32 v = *reinterpret_cast<const u32*>(&tile[tr * 258 + cp * 2]);
            *reinterpret_cast<u32*>(&xtb[(size_t)(t0 + tr) * CC + c0 + cp * 2]) = v;
        }
    } else if (id < 5120) {
        const int id2  = id - 1024;
        const int wsel = id2 >> 10;
        const int i    = ((id2 & 1023) * 256 + tid) * 4;
        const float* src = (wsel == 0) ? Wq : (wsel == 1) ? Wk : (wsel == 2) ? Wv : Wo;
        u16* dst = (wsel < 3) ? (Wcat + (size_t)wsel * CC * CC) : Wob;
        const float4 v = *reinterpret_cast<const float4*>(src + i);
        ushort4 o;
        o.x = f2bf(v.x); o.y = f2bf(v.y); o.z = f2bf(v.z); o.w = f2bf(v.w);
        *reinterpret_cast<ushort4*>(dst + i) = o;
    } else {
        const int idx = ((id - 5120) * 256 + tid) * 4;   // 260*1024 = 266240 exact
        *reinterpret_cast<float4*>(&kvz[idx]) = (float4){0.f, 0.f, 0.f, 0.f};
    }
}

// ---------------------------------------------------------------------------
// kvfuse: per block (head-pair n, 128-row m-tile):
//   1) GEMM: K_tile = xt @ Wk_n^T, V_tile = xt @ Wv_n^T (A shared)
//   2+3) TWO-PASS (t-halves, 48KB peak LDS -> 3 blocks/CU):
//        pass h: waves wm==h write their 64-t half (bias/elu, transposed
//        swizzled [c:128][t:64], idx = c*64 + (t ^ ((c&7)*8))); then ALL
//        waves contract that half: kv[d][e] += sum_t K[d][t]V[e][t],
//        ksum[d] += sum_t K[d][t]; atomicAdd into global (pre-zeroed).
// 1D grid 1024, XCD swizzle: each XCD owns 16 m-panels x all 8 n
// (A panels L2-private; Wk/Wv L2-resident).
// ---------------------------------------------------------------------------
__global__ __launch_bounds__(256, 2) void kvfuse_kernel(
    const u16* __restrict__ A, const u16* __restrict__ Wk,
    const u16* __restrict__ Wv, const float* __restrict__ bk,
    const float* __restrict__ bv, float* __restrict__ kv,
    float* __restrict__ ksum)
{
    __shared__ __align__(16) char smem[49152];
    u16* As  = (u16*)smem;              // [128][64] staging
    u16* WKs = (u16*)(smem + 16384);
    u16* WVs = (u16*)(smem + 32768);

    const int tid  = threadIdx.x;
    const int w    = tid >> 6;
    const int lane = tid & 63;
    const int wm = w >> 1, wn = w & 1;
    const int quad = lane >> 4, l16 = lane & 15;

    // XCD swizzle: bid%8 ~ XCD; XCD k -> m-panels [k*16,(k+1)*16), all n
    const int bid = blockIdx.x;
    const int sw  = (bid & 7) * 128 + (bid >> 3);
    const int n0  = (sw & 7) * 128;      // head-pair channel base
    const int m0  = (sw >> 3) * 128;     // b*T row base

    const int srow = lane >> 3;
    const int scol = ((lane & 7) ^ srow) * 8;

    f32x4 ak[4][4], av[4][4];
    #pragma unroll
    for (int i = 0; i < 4; ++i)
        #pragma unroll
        for (int j = 0; j < 4; ++j) { ak[i][j] = (f32x4)0.0f; av[i][j] = (f32x4)0.0f; }

    for (int k0 = 0; k0 < CC; k0 += 64) {
        __syncthreads();
        #pragma unroll
        for (int s = 0; s < 4; ++s) {
            gl_lds16(A  + (size_t)(m0 + 32 * w + 8 * s + srow) * CC + k0 + scol,
                     &As [(32 * w + 8 * s) * 64]);
            gl_lds16(Wk + (size_t)(n0 + 32 * w + 8 * s + srow) * CC + k0 + scol,
                     &WKs[(32 * w + 8 * s) * 64]);
            gl_lds16(Wv + (size_t)(n0 + 32 * w + 8 * s + srow) * CC + k0 + scol,
                     &WVs[(32 * w + 8 * s) * 64]);
        }
        __syncthreads();

        #pragma unroll
        for (int sub = 0; sub < 2; ++sub) {
            const int pg = (((sub << 2) | quad) ^ (l16 & 7)) * 8;
            bf16x8 af[4], bk4[4], bv4[4];
            #pragma unroll
            for (int i = 0; i < 4; ++i) {
                af[i]  = *reinterpret_cast<const bf16x8*>(&As [(wm * 64 + i * 16 + l16) * 64 + pg]);
                bk4[i] = *reinterpret_cast<const bf16x8*>(&WKs[(wn * 64 + i * 16 + l16) * 64 + pg]);
                bv4[i] = *reinterpret_cast<const bf16x8*>(&WVs[(wn * 64 + i * 16 + l16) * 64 + pg]);
            }
            #pragma unroll
            for (int i = 0; i < 4; ++i)
                #pragma unroll
                for (int j = 0; j < 4; ++j) {
                    ak[i][j] = __builtin_amdgcn_mfma_f32_16x16x32_bf16(af[i], bk4[j], ak[i][j], 0, 0, 0);
                    av[i][j] = __builtin_amdgcn_mfma_f32_16x16x32_bf16(af[i], bv4[j], av[i][j], 0, 0, 0);
                }
        }
    }

    // ---- phases 2+3, two t-passes over [c:128][t:64] tiles (32 KB) ----
    u16* Kl = (u16*)smem;                  // [c:128][t:64] swizzled
    u16* Vl = (u16*)(smem + 16384);

    float bkk[4], bvv[4];
    #pragma unroll
    for (int j = 0; j < 4; ++j) {
        bkk[j] = bk[n0 + wn * 64 + j * 16 + l16];
        bvv[j] = bv[n0 + wn * 64 + j * 16 + l16];
    }

    const int hh    = w >> 1;              // head within pair (for contraction)
    const int dbase = (w & 1) * 32;        // this wave: d-tiles dbase, dbase+16
    const int b     = m0 >> 12;            // m0 / TT
    const int bh    = b * HH + (sw & 7) * 2 + hh;

    FragU ones;
    #pragma unroll
    for (int j = 0; j < 8; ++j) ones.u[j] = (l16 == 0) ? 0x3F80u : 0u;

    f32x4 ckv[2][4], cks[2];
    #pragma unroll
    for (int s = 0; s < 2; ++s) {
        cks[s] = (f32x4)0.0f;
        #pragma unroll
        for (int e4 = 0; e4 < 4; ++e4) ckv[s][e4] = (f32x4)0.0f;
    }

    #pragma unroll
    for (int h = 0; h < 2; ++h) {
        __syncthreads();                   // prior phase reads complete
        if (wm == h) {                     // waves owning this t-half write it
            #pragma unroll
            for (int i = 0; i < 4; ++i) {
                const int t6 = i * 16 + quad * 4;          // 0..60, 4-aligned
                #pragma unroll
                for (int j = 0; j < 4; ++j) {
                    const int c    = wn * 64 + j * 16 + l16;
                    const int toff = t6 ^ ((c & 7) * 8);   // stays in [0,64)
                    ushort4 oK, oV;
                    #pragma unroll
                    for (int r = 0; r < 4; ++r) {
                        float vK = ak[i][j][r] + bkk[j];
                        vK = (vK > 0.0f) ? (vK + 1.0f) : __expf(vK);
                        ((u16*)&oK)[r] = f2bf(vK);
                        ((u16*)&oV)[r] = f2bf(av[i][j][r] + bvv[j]);
                    }
                    *reinterpret_cast<ushort4*>(&Kl[c * 64 + toff]) = oK;
                    *reinterpret_cast<ushort4*>(&Vl[c * 64 + toff]) = oV;
                }
            }
        }
        __syncthreads();
        #pragma unroll
        for (int kt = 0; kt < 2; ++kt) {
            const int tg = kt * 32 + quad * 8;
            #pragma unroll
            for (int s = 0; s < 2; ++s) {
                const int ca = hh * 64 + dbase + s * 16 + l16;
                const bf16x8 af = *reinterpret_cast<const bf16x8*>(
                    &Kl[ca * 64 + (tg ^ ((ca & 7) * 8))]);
                #pragma unroll
                for (int e4 = 0; e4 < 4; ++e4) {
                    const int cb = hh * 64 + e4 * 16 + l16;
                    const bf16x8 bfv = *reinterpret_cast<const bf16x8*>(
                        &Vl[cb * 64 + (tg ^ ((cb & 7) * 8))]);
                    ckv[s][e4] = __builtin_amdgcn_mfma_f32_16x16x32_bf16(af, bfv, ckv[s][e4], 0, 0, 0);
                }
                cks[s] = __builtin_amdgcn_mfma_f32_16x16x32_bf16(af, ones.v, cks[s], 0, 0, 0);
            }
        }
    }

    float* kvb = kv + (size_t)bh * DD * DD;
    #pragma unroll
    for (int s = 0; s < 2; ++s)
        #pragma unroll
        for (int e4 = 0; e4 < 4; ++e4)
            #pragma unroll
            for (int r = 0; r < 4; ++r)
                atomicAdd(&kvb[(dbase + s * 16 + quad * 4 + r) * DD + e4 * 16 + l16],
                          ckv[s][e4][r]);
    if (l16 == 0) {
        #pragma unroll
        for (int s = 0; s < 2; ++s)
            #pragma unroll
            for (int r = 0; r < 4; ++r)
                atomicAdd(&ksum[bh * DD + dbase + s * 16 + quad * 4 + r], cks[s][r]);
    }
}

// ---------------------------------------------------------------------------
// qattn: Q-GEMM (N=1024) with attn fused in the epilogue:
//   Q tile (bias+elu+1) -> swizzled LDS Qt[t:128][c:128]
//   then per wave (head hh=w>>1, t-half th=w&1): num = Q.kv, z = Q.ksum,
//   out = num/(z+1e-6) -> bf16 attn tile (kv/ksum from L2-hot global).
// 1D grid 1024 with the same XCD swizzle.
// ---------------------------------------------------------------------------
__global__ __launch_bounds__(256, 2) void qattn_kernel(
    const u16* __restrict__ A, const u16* __restrict__ Wq,
    const float* __restrict__ bq, const float* __restrict__ kv,
    const float* __restrict__ ksum, u16* __restrict__ attnO)
{
    __shared__ __align__(16) char smem[32768];
    u16* As = (u16*)smem;                  // [128][64]
    u16* Ws = (u16*)(smem + 16384);

    const int tid  = threadIdx.x;
    const int w    = tid >> 6;
    const int lane = tid & 63;
    const int wm = w >> 1, wn = w & 1;
    const int quad = lane >> 4, l16 = lane & 15;
    const int l7 = l16 & 7;

    const int bid = blockIdx.x;
    const int sw  = (bid & 7) * 128 + (bid >> 3);
    const int n0  = (sw & 7) * 128;
    const int m0  = (sw >> 3) * 128;

    const int srow = lane >> 3;
    const int scol = ((lane & 7) ^ srow) * 8;

    f32x4 acc[4][4];
    #pragma unroll
    for (int i = 0; i < 4; ++i)
        #pragma unroll
        for (int j = 0; j < 4; ++j) acc[i][j] = (f32x4)0.0f;

    for (int k0 = 0; k0 < CC; k0 += 64) {
        __syncthreads();
        #pragma unroll
        for (int s = 0; s < 4; ++s) {
            gl_lds16(A  + (size_t)(m0 + 32 * w + 8 * s + srow) * CC + k0 + scol,
                     &As[(32 * w + 8 * s) * 64]);
            gl_lds16(Wq + (size_t)(n0 + 32 * w + 8 * s + srow) * CC + k0 + scol,
                     &Ws[(32 * w + 8 * s) * 64]);
        }
        __syncthreads();

        #pragma unroll
        for (int sub = 0; sub < 2; ++sub) {
            const int pg = (((sub << 2) | quad) ^ l7) * 8;
            bf16x8 af[4], bfr[4];
            #pragma unroll
            for (int i = 0; i < 4; ++i) {
                af[i]  = *reinterpret_cast<const bf16x8*>(&As[(wm * 64 + i * 16 + l16) * 64 + pg]);
                bfr[i] = *reinterpret_cast<const bf16x8*>(&Ws[(wn * 64 + i * 16 + l16) * 64 + pg]);
            }
            #pragma unroll
            for (int i = 0; i < 4; ++i)
                #pragma unroll
                for (int j = 0; j < 4; ++j)
                    acc[i][j] = __builtin_amdgcn_mfma_f32_16x16x32_bf16(af[i], bfr[j], acc[i][j], 0, 0, 0);
        }
    }

    // ---- Q activation -> swizzled LDS tile ----
    __syncthreads();
    u16* Qt = (u16*)smem;                  // [t:128][c:128] swizzled
    float bqq[4];
    #pragma unroll
    for (int j = 0; j < 4; ++j) bqq[j] = bq[n0 + wn * 64 + j * 16 + l16];
    #pragma unroll
    for (int i = 0; i < 4; ++i) {
        #pragma unroll
        for (int j = 0; j < 4; ++j) {
            const int c = wn * 64 + j * 16 + l16;
            #pragma unroll
            for (int r = 0; r < 4; ++r) {
                const int t = wm * 64 + i * 16 + quad * 4 + r;
                float v = acc[i][j][r] + bqq[j];
                v = (v > 0.0f) ? (v + 1.0f) : __expf(v);
                Qt[t * 128 + (c ^ ((t & 7) * 8))] = f2bf(v);
            }
        }
    }
    __syncthreads();

    // ---- attn epilogue: wave -> head hh, t-half th ----
    const int hh = w >> 1, th = w & 1;
    const int b  = m0 >> 12;
    const int bh = b * HH + (sw & 7) * 2 + hh;
    const float* kvh = kv + (size_t)bh * DD * DD;

    FragU bf[4][2], zb[2];
    #pragma unroll
    for (int ck = 0; ck < 2; ++ck) {
        #pragma unroll
        for (int nt = 0; nt < 4; ++nt)
            #pragma unroll
            for (int j = 0; j < 8; ++j)
                bf[nt][ck].u[j] = f2bf(kvh[(ck * 32 + quad * 8 + j) * DD + nt * 16 + l16]);
        #pragma unroll
        for (int j = 0; j < 8; ++j)
            zb[ck].u[j] = (l16 == 0) ? f2bf(ksum[bh * DD + ck * 32 + quad * 8 + j]) : 0u;
    }

    f32x4 a2[4][4], za[4];
    #pragma unroll
    for (int i = 0; i < 4; ++i) {
        za[i] = (f32x4)0.0f;
        #pragma unroll
        for (int j = 0; j < 4; ++j) a2[i][j] = (f32x4)0.0f;
    }

    #pragma unroll
    for (int i = 0; i < 4; ++i) {
        const int trow = th * 64 + i * 16 + l16;
        #pragma unroll
        for (int ck = 0; ck < 2; ++ck) {
            const bf16x8 af = *reinterpret_cast<const bf16x8*>(
                &Qt[trow * 128 + (((hh * 8 + ck * 4 + quad) ^ l7) * 8)]);
            #pragma unroll
            for (int nt = 0; nt < 4; ++nt)
                a2[i][nt] = __builtin_amdgcn_mfma_f32_16x16x32_bf16(af, bf[nt][ck].v, a2[i][nt], 0, 0, 0);
            za[i] = __builtin_amdgcn_mfma_f32_16x16x32_bf16(af, zb[ck].v, za[i], 0, 0, 0);
        }
    }

    #pragma unroll
    for (int i = 0; i < 4; ++i) {
        float inv[4];
        #pragma unroll
        for (int r = 0; r < 4; ++r) {
            const float zv = __shfl(za[i][r], lane & 48);
            inv[r] = 1.0f / (zv + 1e-6f);
        }
        #pragma unroll
        for (int nt = 0; nt < 4; ++nt) {
            #pragma unroll
            for (int r = 0; r < 4; ++r) {
                const size_t row = (size_t)(m0 + th * 64 + i * 16 + quad * 4 + r);
                const int    col = n0 + hh * 64 + nt * 16 + l16;
                attnO[row * CC + col] = f2bf(a2[i][nt][r] * inv[r]);
            }
        }
    }
}

// ---------------------------------------------------------------------------
// Out-proj GEMM (MODE 2): 128x128 tile, +bias +fp32 residual, LDS-bounced
// fp32 stores along T.  1D grid 1024 with the same XCD swizzle.
// ---------------------------------------------------------------------------
template <int MODE>
__global__ __launch_bounds__(256, 2) void gemm_kernel(
    const u16* __restrict__ A, const u16* __restrict__ W,
    const float* __restrict__ b0, const float* __restrict__ b1,
    const float* __restrict__ b2, u16* __restrict__ Ybf,
    float* __restrict__ Yf, const float* __restrict__ xres,
    int M, int N, int K)
{
    __shared__ char smem[34048];           // As+Ws (32KB) / Cs (64*133*4)
    u16* As = (u16*)smem;                  // [128][64]
    u16* Ws = (u16*)(smem + 16384);        // [128][64]

    const int tid  = threadIdx.x;
    const int w    = tid >> 6;
    const int lane = tid & 63;
    const int wm = w >> 1, wn = w & 1;
    const int quad = lane >> 4, l16 = lane & 15;

    const int bid = blockIdx.x;
    const int sw  = (bid & 7) * 128 + (bid >> 3);
    const int n0  = (sw & 7) * 128;
    const int m0  = (sw >> 3) * 128;

    const int srow = lane >> 3;
    const int scol = ((lane & 7) ^ srow) * 8;

    f32x4 acc[4][4];
    #pragma unroll
    for (int i = 0; i < 4; ++i)
        #pragma unroll
        for (int j = 0; j < 4; ++j) acc[i][j] = (f32x4)0.0f;

    for (int k0 = 0; k0 < K; k0 += 64) {
        __syncthreads();
        #pragma unroll
        for (int s = 0; s < 4; ++s)
            gl_lds16(A + (size_t)(m0 + 32 * w + 8 * s + srow) * K + k0 + scol,
                     &As[(32 * w + 8 * s) * 64]);
        #pragma unroll
        for (int s = 0; s < 4; ++s)
            gl_lds16(W + (size_t)(n0 + 32 * w + 8 * s + srow) * K + k0 + scol,
                     &Ws[(32 * w + 8 * s) * 64]);
        __syncthreads();

        #pragma unroll
        for (int sub = 0; sub < 2; ++sub) {
            const int pg = (((sub << 2) | quad) ^ (l16 & 7)) * 8;
            bf16x8 af[4], bfr[4];
            #pragma unroll
            for (int i = 0; i < 4; ++i) {
                af[i]  = *reinterpret_cast<const bf16x8*>(&As[(wm * 64 + i * 16 + l16) * 64 + pg]);
                bfr[i] = *reinterpret_cast<const bf16x8*>(&Ws[(wn * 64 + i * 16 + l16) * 64 + pg]);
            }
            #pragma unroll
            for (int i = 0; i < 4; ++i)
                #pragma unroll
                for (int j = 0; j < 4; ++j)
                    acc[i][j] = __builtin_amdgcn_mfma_f32_16x16x32_bf16(af[i], bfr[j], acc[i][j], 0, 0, 0);
        }
    }

    if (MODE == 2) {
        float* Cs = (float*)smem;          // [64][133]
        const int b     = m0 / TT;
        const int tbase = m0 - b * TT;
        const int cl    = lane >> 4;
        #pragma unroll
        for (int hh = 0; hh < 2; ++hh) {
            __syncthreads();
            if (wm == hh) {
                #pragma unroll
                for (int i = 0; i < 4; ++i)
                    #pragma unroll
                    for (int j = 0; j < 4; ++j)
                        #pragma unroll
                        for (int r = 0; r < 4; ++r)
                            Cs[(i * 16 + quad * 4 + r) * 133 + wn * 64 + j * 16 + l16] = acc[i][j][r];
            }
            __syncthreads();
            #pragma unroll
            for (int p = 0; p < 8; ++p) {
                const int col = p * 16 + w * 4 + cl;
                const int tl  = l16 * 4;
                float4 v;
                v.x = Cs[(tl + 0) * 133 + col];
                v.y = Cs[(tl + 1) * 133 + col];
                v.z = Cs[(tl + 2) * 133 + col];
                v.w = Cs[(tl + 3) * 133 + col];
                const float bv = b0[n0 + col];
                const size_t base = ((size_t)b * CC + n0 + col) * TT + tbase + hh * 64 + tl;
                const float4 rx = *reinterpret_cast<const float4*>(&xres[base]);
                v.x += bv + rx.x; v.y += bv + rx.y;
                v.z += bv + rx.z; v.w += bv + rx.w;
                *reinterpret_cast<float4*>(&Yf[base]) = v;
            }
        }
    }
}

// ---------------------------------------------------------------------------
extern "C" void kernel_launch(void* const* d_in, const int* in_sizes, int n_in,
                              void* d_out, int out_size, void* d_ws, size_t ws_size,
                              hipStream_t stream)
{
    const float* x  = (const float*)d_in[0];
    const float* Wq = (const float*)d_in[1];
    const float* bq = (const float*)d_in[2];
    const float* Wk = (const float*)d_in[3];
    const float* bk = (const float*)d_in[4];
    const float* Wv = (const float*)d_in[5];
    const float* bv = (const float*)d_in[6];
    const float* Wo = (const float*)d_in[7];
    const float* bo = (const float*)d_in[8];
    float* out = (float*)d_out;

    const int M = BB * TT;                                   // 16384
    const size_t BUF  = (size_t)BB * TT * CC * sizeof(u16);  // 32 MiB
    const size_t WBUF = (size_t)CC * CC * sizeof(u16);       // 2 MiB

    char* ws = (char*)d_ws;
    u16* xt   = (u16*)(ws);                // xt bf16 [B*T][C]
    u16* Qb   = (u16*)(ws + BUF);          // attn output [B*T][C]
    u16* Wcat = (u16*)(ws + 4 * BUF);      // [3072][1024] bf16 (Q,K,V)
    u16* Wob  = (u16*)(ws + 4 * BUF + 3 * WBUF);
    float* kvbuf = (float*)(ws + 4 * BUF + 4 * WBUF);        // 1 MiB + 16 KiB (incl ksum)
    float* ksumb = kvbuf + (size_t)BB * HH * DD * DD;

    // prep: transpose (1024) + weight cvt (4096) + kv zero (260)
    prep_kernel<<<5380, 256, 0, stream>>>(x, Wq, Wk, Wv, Wo, xt, Wcat, Wob, kvbuf);

    // fused K/V GEMM + kv/ksum contraction (atomic accumulate)
    kvfuse_kernel<<<1024, 256, 0, stream>>>(
        xt, Wcat + (size_t)CC * CC, Wcat + 2 * (size_t)CC * CC, bk, bv, kvbuf, ksumb);

    // fused Q GEMM + attention epilogue -> attn tile in Qb
    qattn_kernel<<<1024, 256, 0, stream>>>(
        xt, Wcat, bq, kvbuf, ksumb, Qb);

    // out-proj + bias + residual -> fp32 [B][C][T]
    gemm_kernel<2><<<1024, 256, 0, stream>>>(
        Qb, Wob, bo, nullptr, nullptr, nullptr, out, x, M, CC, CC);
}